// Round 7
// baseline (963.016 us; speedup 1.0000x reference)
//
#include <hip/hip_runtime.h>

#define BB 1024
#define FF 64
#define SS 512
#define HH 128
#define ZP 200          // z row pitch in bf16 elems (192 data + 8 pad)
#define OUTS (BB*FF)

typedef __attribute__((ext_vector_type(8))) short bf16x8;
typedef __attribute__((ext_vector_type(4))) float f32x4;

__device__ __forceinline__ unsigned short f2bf(float f) {
    unsigned int u = __float_as_uint(f);
    u += 0x7fff + ((u >> 16) & 1);          // RNE
    return (unsigned short)(u >> 16);
}

// LDS-only barrier: ds ops drain (lgkmcnt 0) but global loads/stores ride
// across. sched_barrier(0) fences compiler reordering (rule #18).
__device__ __forceinline__ void bar_lds() {
    asm volatile("s_waitcnt lgkmcnt(0)" ::: "memory");
    __builtin_amdgcn_s_barrier();
    __builtin_amdgcn_sched_barrier(0);
}

// ---------------------------------------------------------------------------
// 64 blocks x 512 threads (8 waves). Block owns 16 batch rows -> the MFMA
// M-dim is FULLY used (r6 carried only 4 real rows -> 75% of every MFMA
// wasted). Wave w owns hidden units [16w,16w+16): gate cols {16w+128g}.
// Lane l handles rows 4*(l>>4)+{0..3} via acc regs 0..3 (C-layout m89).
// z = [x_hat(64) | h(128)] bf16 in LDS, double-buffered; weights bf16
// B-fragments register-resident (identical layout to r6, which verified).
// ---------------------------------------------------------------------------
__global__ __launch_bounds__(512)
void lstm_mfma_kernel(const float* __restrict__ x,
                      const int* __restrict__ available_len,
                      const int* __restrict__ predict_len,
                      const float* __restrict__ W_ih,
                      const float* __restrict__ W_hh,
                      const float* __restrict__ b_ih,
                      const float* __restrict__ b_hh,
                      const float* __restrict__ W_den,
                      const float* __restrict__ b_den,
                      const float* __restrict__ init_ch,
                      float* __restrict__ out)
{
    const int b0  = blockIdx.x * 16;
    const int tid = threadIdx.x;
    const int w   = tid >> 6;          // wave 0..7
    const int l   = tid & 63;
    const int l16 = l & 15;
    const int lq  = l >> 4;            // 0..3
    const bool w4 = (w < 4);

    __shared__ __align__(16) unsigned short zbuf[2][16 * ZP];

    for (int i = tid; i < 2 * 16 * ZP / 2; i += 512)
        ((unsigned int*)zbuf)[i] = 0u;

    // block maxP (uniform scalar)
    int maxP = 1;
    #pragma unroll
    for (int i = 0; i < 16; i++) maxP = max(maxP, predict_len[b0 + i]);

    // lane's 4 rows: b0 + 4*lq + r
    int Pv[4], Av[4];
    #pragma unroll
    for (int r = 0; r < 4; r++) {
        Pv[r] = predict_len[b0 + 4*lq + r];
        Av[r] = available_len[b0 + 4*lq + r];
    }

    // ---- gate weights: wg[gate][ktile 0..5] (B-frag: col n, k 32kt+8lq) ----
    bf16x8 wg[4][6];
    float bias[4];
    #pragma unroll
    for (int g = 0; g < 4; ++g) {
        const int n = 128*g + 16*w + l16;
        const float* rih = W_ih + n * FF;
        const float* rhh = W_hh + n * HH;
        #pragma unroll
        for (int kt = 0; kt < 6; ++kt) {
            const int k = 32*kt + 8*lq;
            const float* src = (k < 64) ? (rih + k) : (rhh + (k - 64));
            bf16x8 r;
            #pragma unroll
            for (int i = 0; i < 8; i++) r[i] = (short)f2bf(src[i]);
            wg[g][kt] = r;
        }
        bias[g] = b_ih[n] + b_hh[n];
    }

    // pred weights (waves 0-3): feature f = 16w + l16
    bf16x8 wd0, wd1, wd2, wd3;
    float bden = 0.f;
    if (w4) {
        const int f = 16*w + l16;
        const float* rd = W_den + f * HH;
        bf16x8 r;
        #pragma unroll
        for (int i = 0; i < 8; i++) r[i] = (short)f2bf(rd[0*32 + 8*lq + i]);
        wd0 = r;
        #pragma unroll
        for (int i = 0; i < 8; i++) r[i] = (short)f2bf(rd[1*32 + 8*lq + i]);
        wd1 = r;
        #pragma unroll
        for (int i = 0; i < 8; i++) r[i] = (short)f2bf(rd[2*32 + 8*lq + i]);
        wd2 = r;
        #pragma unroll
        for (int i = 0; i < 8; i++) r[i] = (short)f2bf(rd[3*32 + 8*lq + i]);
        wd3 = r;
        bden = b_den[f];
    }

    // x duty: every wave streams rows {w, w+8}, feature l
    const size_t xb1 = ((size_t)(b0 + w)     * FF + l) * SS;
    const size_t xb2 = ((size_t)(b0 + w + 8) * FF + l) * SS;
    const int AX1 = available_len[b0 + w];
    const int AX2 = available_len[b0 + w + 8];

    const int unit  = 16*w + l16;
    const int abase = l16*ZP + 8*lq;
    float cc[4];
    const float c0v = init_ch[unit];
    #pragma unroll
    for (int r = 0; r < 4; r++) cc[r] = c0v;
    const unsigned short h0b = f2bf(init_ch[HH + unit]);
    float* outp = out + (size_t)(b0 + 4*lq) * FF + 16*w + l16;

    bar_lds();                          // zeroing visible

    #pragma unroll
    for (int r = 0; r < 4; r++) zbuf[0][(4*lq + r)*ZP + 64 + unit] = h0b;
    zbuf[0][w*ZP + l]       = f2bf(x[xb1]);
    zbuf[0][(w + 8)*ZP + l] = f2bf(x[xb2]);

    float4 q1 = {0.f,0.f,0.f,0.f}, q2 = {0.f,0.f,0.f,0.f};
    if (AX1 > 1) q1 = *(const float4*)(x + xb1);
    if (AX2 > 1) q2 = *(const float4*)(x + xb2);

    int cur = 0;

#define DO_STEP(S, XN1, XN2)                                                   \
  do {                                                                         \
    const int s_ = (S);                                                        \
    bar_lds();                                          /* B1 */               \
    const unsigned short* zc_ = zbuf[cur];                                     \
    bf16x8 a0 = *(const bf16x8*)(zc_ + abase +   0);                           \
    bf16x8 a1 = *(const bf16x8*)(zc_ + abase +  32);                           \
    bf16x8 a2 = *(const bf16x8*)(zc_ + abase +  64);                           \
    bf16x8 a3 = *(const bf16x8*)(zc_ + abase +  96);                           \
    bf16x8 a4 = *(const bf16x8*)(zc_ + abase + 128);                           \
    bf16x8 a5 = *(const bf16x8*)(zc_ + abase + 160);                           \
    f32x4 ac0 = {0.f,0.f,0.f,0.f}, ac1 = {0.f,0.f,0.f,0.f},                    \
          ac2 = {0.f,0.f,0.f,0.f}, ac3 = {0.f,0.f,0.f,0.f};                    \
    ac0 = __builtin_amdgcn_mfma_f32_16x16x32_bf16(a0, wg[0][0], ac0, 0,0,0);   \
    ac1 = __builtin_amdgcn_mfma_f32_16x16x32_bf16(a0, wg[1][0], ac1, 0,0,0);   \
    ac2 = __builtin_amdgcn_mfma_f32_16x16x32_bf16(a0, wg[2][0], ac2, 0,0,0);   \
    ac3 = __builtin_amdgcn_mfma_f32_16x16x32_bf16(a0, wg[3][0], ac3, 0,0,0);   \
    ac0 = __builtin_amdgcn_mfma_f32_16x16x32_bf16(a1, wg[0][1], ac0, 0,0,0);   \
    ac1 = __builtin_amdgcn_mfma_f32_16x16x32_bf16(a1, wg[1][1], ac1, 0,0,0);   \
    ac2 = __builtin_amdgcn_mfma_f32_16x16x32_bf16(a1, wg[2][1], ac2, 0,0,0);   \
    ac3 = __builtin_amdgcn_mfma_f32_16x16x32_bf16(a1, wg[3][1], ac3, 0,0,0);   \
    ac0 = __builtin_amdgcn_mfma_f32_16x16x32_bf16(a2, wg[0][2], ac0, 0,0,0);   \
    ac1 = __builtin_amdgcn_mfma_f32_16x16x32_bf16(a2, wg[1][2], ac1, 0,0,0);   \
    ac2 = __builtin_amdgcn_mfma_f32_16x16x32_bf16(a2, wg[2][2], ac2, 0,0,0);   \
    ac3 = __builtin_amdgcn_mfma_f32_16x16x32_bf16(a2, wg[3][2], ac3, 0,0,0);   \
    ac0 = __builtin_amdgcn_mfma_f32_16x16x32_bf16(a3, wg[0][3], ac0, 0,0,0);   \
    ac1 = __builtin_amdgcn_mfma_f32_16x16x32_bf16(a3, wg[1][3], ac1, 0,0,0);   \
    ac2 = __builtin_amdgcn_mfma_f32_16x16x32_bf16(a3, wg[2][3], ac2, 0,0,0);   \
    ac3 = __builtin_amdgcn_mfma_f32_16x16x32_bf16(a3, wg[3][3], ac3, 0,0,0);   \
    ac0 = __builtin_amdgcn_mfma_f32_16x16x32_bf16(a4, wg[0][4], ac0, 0,0,0);   \
    ac1 = __builtin_amdgcn_mfma_f32_16x16x32_bf16(a4, wg[1][4], ac1, 0,0,0);   \
    ac2 = __builtin_amdgcn_mfma_f32_16x16x32_bf16(a4, wg[2][4], ac2, 0,0,0);   \
    ac3 = __builtin_amdgcn_mfma_f32_16x16x32_bf16(a4, wg[3][4], ac3, 0,0,0);   \
    ac0 = __builtin_amdgcn_mfma_f32_16x16x32_bf16(a5, wg[0][5], ac0, 0,0,0);   \
    ac1 = __builtin_amdgcn_mfma_f32_16x16x32_bf16(a5, wg[1][5], ac1, 0,0,0);   \
    ac2 = __builtin_amdgcn_mfma_f32_16x16x32_bf16(a5, wg[2][5], ac2, 0,0,0);   \
    ac3 = __builtin_amdgcn_mfma_f32_16x16x32_bf16(a5, wg[3][5], ac3, 0,0,0);   \
    const int nxt_ = cur ^ 1;                                                  \
    _Pragma("unroll")                                                          \
    for (int r = 0; r < 4; r++) {                                              \
      const float g0 = ac0[r] + bias[0];                                       \
      const float g1 = ac1[r] + bias[1];                                       \
      const float g2 = ac2[r] + bias[2];                                       \
      const float g3 = ac3[r] + bias[3];                                       \
      const float si = 1.f / (1.f + __expf(-g0));                              \
      const float sf = 1.f / (1.f + __expf(-g1));                              \
      const float tg = 1.f - 2.f / (__expf(2.f * g2) + 1.f);                   \
      const float so = 1.f / (1.f + __expf(-g3));                              \
      const float cn = sf * cc[r] + si * tg;                                   \
      const float tc = 1.f - 2.f / (__expf(2.f * cn) + 1.f);                   \
      const float hn = so * tc;                                                \
      if (s_ < Pv[r]) {                                                        \
        cc[r] = cn;                                                            \
        zbuf[nxt_][(4*lq + r)*ZP + 64 + unit] = f2bf(hn);                      \
      }                                                                        \
    }                                                                          \
    if (s_ + 1 < AX1) zbuf[nxt_][w*ZP + l]       = f2bf(XN1);                  \
    if (s_ + 1 < AX2) zbuf[nxt_][(w + 8)*ZP + l] = f2bf(XN2);                  \
    bar_lds();                                          /* B2: h ready */      \
    if (w4) {                                                                  \
      const unsigned short* zn_ = zbuf[nxt_];                                  \
      bf16x8 h0f = *(const bf16x8*)(zn_ + abase + 64 +  0);                    \
      bf16x8 h1f = *(const bf16x8*)(zn_ + abase + 64 + 32);                    \
      bf16x8 h2f = *(const bf16x8*)(zn_ + abase + 64 + 64);                    \
      bf16x8 h3f = *(const bf16x8*)(zn_ + abase + 64 + 96);                    \
      f32x4 pa = {0.f,0.f,0.f,0.f}, pb = {0.f,0.f,0.f,0.f};                    \
      pa = __builtin_amdgcn_mfma_f32_16x16x32_bf16(h0f, wd0, pa, 0,0,0);       \
      pb = __builtin_amdgcn_mfma_f32_16x16x32_bf16(h2f, wd2, pb, 0,0,0);       \
      pa = __builtin_amdgcn_mfma_f32_16x16x32_bf16(h1f, wd1, pa, 0,0,0);       \
      pb = __builtin_amdgcn_mfma_f32_16x16x32_bf16(h3f, wd3, pb, 0,0,0);       \
      _Pragma("unroll")                                                        \
      for (int r = 0; r < 4; r++) {                                            \
        if (s_ < Pv[r]) {                                                      \
          const float pred_ = pa[r] + pb[r] + bden;                            \
          outp[(size_t)s_ * OUTS + r * FF] = pred_;                            \
          if (s_ + 1 >= Av[r])                                                 \
            zbuf[nxt_][(4*lq + r)*ZP + 16*w + l16] = f2bf(pred_);              \
        }                                                                      \
      }                                                                        \
    }                                                                          \
    cur = nxt_;                                                                \
  } while (0)

    int t4 = 0;
    for (; t4 + 4 <= maxP; t4 += 4) {
        float4 qn1 = {0.f,0.f,0.f,0.f}, qn2 = {0.f,0.f,0.f,0.f};
        if (t4 + 4 < AX1) qn1 = *(const float4*)(x + xb1 + t4 + 4);
        if (t4 + 4 < AX2) qn2 = *(const float4*)(x + xb2 + t4 + 4);
        DO_STEP(t4 + 0, q1.y, q2.y);
        DO_STEP(t4 + 1, q1.z, q2.z);
        DO_STEP(t4 + 2, q1.w, q2.w);
        DO_STEP(t4 + 3, qn1.x, qn2.x);
        q1 = qn1; q2 = qn2;
    }
    for (; t4 < maxP; ++t4) {
        float xs1 = 0.f, xs2 = 0.f;
        if (t4 + 1 < AX1) xs1 = x[xb1 + t4 + 1];
        if (t4 + 1 < AX2) xs2 = x[xb2 + t4 + 1];
        DO_STEP(t4, xs1, xs2);
    }
#undef DO_STEP
}

// ---------------------------------------------------------------------------
// Tail: for t >= predict_len[b], out[t][b][f] = x[b][f][t].
// ---------------------------------------------------------------------------
__global__ void tail_copy(const float* __restrict__ x,
                          const int* __restrict__ predict_len,
                          float* __restrict__ out)
{
    __shared__ float tile[64][65];
    const int b  = blockIdx.x;
    const int t0 = blockIdx.y * 64;
    const int P  = predict_len[b];
    if (t0 + 64 <= P) return;

    const int tid = threadIdx.x;         // 256
    const int tt  = tid & 63;
    const int fb  = tid >> 6;
    #pragma unroll
    for (int i = 0; i < 16; i++) {
        int f = fb * 16 + i;
        tile[f][tt] = x[(size_t)b * FF * SS + (size_t)f * SS + t0 + tt];
    }
    __syncthreads();
    const int f2 = tid & 63;
    const int tb = tid >> 6;
    #pragma unroll
    for (int i = 0; i < 16; i++) {
        int tloc = tb * 16 + i;
        int t    = t0 + tloc;
        if (t >= P) out[(size_t)t * BB * FF + (size_t)b * FF + f2] = tile[f2][tloc];
    }
}

extern "C" void kernel_launch(void* const* d_in, const int* in_sizes, int n_in,
                              void* d_out, int out_size, void* d_ws, size_t ws_size,
                              hipStream_t stream) {
    const float* x       = (const float*)d_in[0];
    const int*   avail   = (const int*)  d_in[1];
    const int*   plen    = (const int*)  d_in[2];
    const float* W_ih    = (const float*)d_in[3];
    const float* W_hh    = (const float*)d_in[4];
    const float* b_ih    = (const float*)d_in[5];
    const float* b_hh    = (const float*)d_in[6];
    const float* W_den   = (const float*)d_in[7];
    const float* b_den   = (const float*)d_in[8];
    const float* init_ch = (const float*)d_in[9];
    float*       out     = (float*)d_out;

    tail_copy<<<dim3(BB, SS/64), dim3(256), 0, stream>>>(x, plen, out);
    lstm_mfma_kernel<<<dim3(BB/16), dim3(512), 0, stream>>>(
        x, avail, plen, W_ih, W_hh, b_ih, b_hh, W_den, b_den, init_ch, out);
}

// Round 10
// 444.906 us; speedup vs baseline: 2.1645x; 2.1645x over previous
//
#include <hip/hip_runtime.h>

#define BB 1024
#define FF 64
#define SS 512
#define HH 128
#define ZP 200          // z row pitch in bf16 elems (192 data + 8 pad)
#define ZROWS 16
#define OUTS (BB*FF)

typedef __attribute__((ext_vector_type(8))) short bf16x8;
typedef __attribute__((ext_vector_type(4))) float f32x4;

__device__ __forceinline__ unsigned short f2bf(float f) {
    unsigned int u = __float_as_uint(f);
    u += 0x7fff + ((u >> 16) & 1);          // RNE
    return (unsigned short)(u >> 16);
}

// LDS-only barrier: fused waitcnt+s_barrier under one "memory" clobber;
// sched_barrier(0) fences the machine scheduler on both sides (rule #18).
__device__ __forceinline__ void bar_lds() {
    __builtin_amdgcn_sched_barrier(0);
    asm volatile("s_waitcnt lgkmcnt(0)\n\ts_barrier" ::: "memory");
    __builtin_amdgcn_sched_barrier(0);
}

// ---------------------------------------------------------------------------
// Fold kernel: W_fold[n][k] = sum_f W_ih[n][f]*W_den[f][k],
// b_fold[n]   = sum_f W_ih[n][f]*b_den[f].
// ws[0..65535] = W_fold, ws[65536..66047] = b_fold.
// ---------------------------------------------------------------------------
__global__ void fold_kernel(const float* __restrict__ W_ih,
                            const float* __restrict__ W_den,
                            const float* __restrict__ b_den,
                            float* __restrict__ ws)
{
    const int n = blockIdx.x;      // 512
    const int k = threadIdx.x;     // 128
    float s = 0.f;
    #pragma unroll 8
    for (int f = 0; f < FF; ++f) s = fmaf(W_ih[n*FF + f], W_den[f*HH + k], s);
    ws[n*HH + k] = s;
    if (k == 0) {
        float bsum = 0.f;
        #pragma unroll 8
        for (int f = 0; f < FF; ++f) bsum = fmaf(W_ih[n*FF + f], b_den[f], bsum);
        ws[4*HH*HH + n] = bsum;
    }
}

// ---------------------------------------------------------------------------
// Main recurrence. 256 blocks x 512 threads; block owns 4 batch rows at
// M-rows {0,4,8,12}; lane's acc[0] = its row. Wave w owns units [16w,16w+16).
// PHASE 1 (t < maxAV): r6 two-barrier step — z=[x_hat|h], explicit pred
//   feedback AND teacher-x staging at B2 (r8/r9 bug: the XNEXT write was
//   dropped -> stale teacher inputs; restored here).
// PHASE 2 (t >= maxAV, all rows auto): W_auto = W_hh + W_ih@W_den fold
//   (validated r3), ONE barrier/step, deferred pred store.
// ---------------------------------------------------------------------------
__global__ __launch_bounds__(512)
void lstm_mfma_kernel(const float* __restrict__ x,
                      const int* __restrict__ available_len,
                      const int* __restrict__ predict_len,
                      const float* __restrict__ W_ih,
                      const float* __restrict__ W_hh,
                      const float* __restrict__ b_ih,
                      const float* __restrict__ b_hh,
                      const float* __restrict__ W_den,
                      const float* __restrict__ b_den,
                      const float* __restrict__ init_ch,
                      const float* __restrict__ ws,
                      float* __restrict__ out)
{
    const int b0  = blockIdx.x * 4;
    const int tid = threadIdx.x;
    const int w   = tid >> 6;          // wave 0..7
    const int l   = tid & 63;
    const int l16 = l & 15;
    const int lq  = l >> 4;            // 0..3
    const bool w4 = (w < 4);

    __shared__ __align__(16) unsigned short zbuf[2][ZROWS * ZP];

    for (int i = tid; i < 2 * ZROWS * ZP / 2; i += 512)
        ((unsigned int*)zbuf)[i] = 0u;

    const int p0 = predict_len[b0], p1 = predict_len[b0+1],
              p2 = predict_len[b0+2], p3 = predict_len[b0+3];
    const int a0i = available_len[b0], a1i = available_len[b0+1],
              a2i = available_len[b0+2], a3i = available_len[b0+3];
    const int maxP  = max(max(p0, p1), max(p2, p3));
    const int tsw   = max(max(a0i, a1i), max(a2i, a3i));   // phase switch
    const int P_my  = predict_len[b0 + lq];     // lane's row (acc reg 0)
    const int AV_my = available_len[b0 + lq];

    // ---- gate weights: wg[gate][ktile 0..5], bf16, register-resident ----
    bf16x8 wg[4][6];
    float bias[4];
    #pragma unroll
    for (int g = 0; g < 4; ++g) {
        const int n = 128*g + 16*w + l16;
        const float* rih = W_ih + n * FF;
        const float* rhh = W_hh + n * HH;
        #pragma unroll
        for (int kt = 0; kt < 6; ++kt) {
            const int k = 32*kt + 8*lq;
            const float* src = (k < 64) ? (rih + k) : (rhh + (k - 64));
            bf16x8 r;
            #pragma unroll
            for (int i = 0; i < 8; i++) r[i] = (short)f2bf(src[i]);
            wg[g][kt] = r;
        }
        bias[g] = b_ih[n] + b_hh[n];
    }

    // pred weights (waves 0-3): f = 16w + l16
    bf16x8 wd0, wd1, wd2, wd3;
    float bden = 0.f;
    size_t xbase = 0;
    int AV_x = 0;
    if (w4) {
        const int f = 16*w + l16;
        const float* rd = W_den + f * HH;
        bf16x8 r;
        #pragma unroll
        for (int i = 0; i < 8; i++) r[i] = (short)f2bf(rd[0*32 + 8*lq + i]);
        wd0 = r;
        #pragma unroll
        for (int i = 0; i < 8; i++) r[i] = (short)f2bf(rd[1*32 + 8*lq + i]);
        wd1 = r;
        #pragma unroll
        for (int i = 0; i < 8; i++) r[i] = (short)f2bf(rd[2*32 + 8*lq + i]);
        wd2 = r;
        #pragma unroll
        for (int i = 0; i < 8; i++) r[i] = (short)f2bf(rd[3*32 + 8*lq + i]);
        wd3 = r;
        bden = b_den[f];
        xbase = ((size_t)(b0 + w) * FF + l) * SS;   // x duty: row b0+w, feature l
        AV_x  = available_len[b0 + w];
    }

    const int unit  = 16*w + l16;
    const int abase = l16*ZP + 8*lq;
    float c = init_ch[unit];
    const float h0v = init_ch[HH + unit];
    float* outb = out + (size_t)(b0 + lq) * FF + 16*w + l16;

    bar_lds();                          // zeroing visible before init writes

    zbuf[0][(4*lq)*ZP + 64 + unit] = f2bf(h0v);
    if (w4) zbuf[0][(4*w)*ZP + l] = f2bf(x[xbase]);

    float4 qc = {0.f,0.f,0.f,0.f};
    if (w4 && AV_x > 1) qc = *(const float4*)(x + xbase);   // x_0..x_3

    int cur = 0;

    // ================= PHASE 1: t in [0, tsw) — r6 structure ================
#define DO_STEP(S, XNEXT)                                                      \
  do {                                                                         \
    const int s_ = (S);                                                        \
    bar_lds();                                          /* B1: buf[cur] */     \
    const unsigned short* zc_ = zbuf[cur];                                     \
    bf16x8 a0 = *(const bf16x8*)(zc_ + abase +   0);                           \
    bf16x8 a1 = *(const bf16x8*)(zc_ + abase +  32);                           \
    bf16x8 a2 = *(const bf16x8*)(zc_ + abase +  64);                           \
    bf16x8 a3 = *(const bf16x8*)(zc_ + abase +  96);                           \
    bf16x8 a4 = *(const bf16x8*)(zc_ + abase + 128);                           \
    bf16x8 a5 = *(const bf16x8*)(zc_ + abase + 160);                           \
    f32x4 ac0 = {0.f,0.f,0.f,0.f}, ac1 = {0.f,0.f,0.f,0.f},                    \
          ac2 = {0.f,0.f,0.f,0.f}, ac3 = {0.f,0.f,0.f,0.f};                    \
    ac0 = __builtin_amdgcn_mfma_f32_16x16x32_bf16(a0, wg[0][0], ac0, 0,0,0);   \
    ac1 = __builtin_amdgcn_mfma_f32_16x16x32_bf16(a0, wg[1][0], ac1, 0,0,0);   \
    ac2 = __builtin_amdgcn_mfma_f32_16x16x32_bf16(a0, wg[2][0], ac2, 0,0,0);   \
    ac3 = __builtin_amdgcn_mfma_f32_16x16x32_bf16(a0, wg[3][0], ac3, 0,0,0);   \
    ac0 = __builtin_amdgcn_mfma_f32_16x16x32_bf16(a1, wg[0][1], ac0, 0,0,0);   \
    ac1 = __builtin_amdgcn_mfma_f32_16x16x32_bf16(a1, wg[1][1], ac1, 0,0,0);   \
    ac2 = __builtin_amdgcn_mfma_f32_16x16x32_bf16(a1, wg[2][1], ac2, 0,0,0);   \
    ac3 = __builtin_amdgcn_mfma_f32_16x16x32_bf16(a1, wg[3][1], ac3, 0,0,0);   \
    ac0 = __builtin_amdgcn_mfma_f32_16x16x32_bf16(a2, wg[0][2], ac0, 0,0,0);   \
    ac1 = __builtin_amdgcn_mfma_f32_16x16x32_bf16(a2, wg[1][2], ac1, 0,0,0);   \
    ac2 = __builtin_amdgcn_mfma_f32_16x16x32_bf16(a2, wg[2][2], ac2, 0,0,0);   \
    ac3 = __builtin_amdgcn_mfma_f32_16x16x32_bf16(a2, wg[3][2], ac3, 0,0,0);   \
    ac0 = __builtin_amdgcn_mfma_f32_16x16x32_bf16(a3, wg[0][3], ac0, 0,0,0);   \
    ac1 = __builtin_amdgcn_mfma_f32_16x16x32_bf16(a3, wg[1][3], ac1, 0,0,0);   \
    ac2 = __builtin_amdgcn_mfma_f32_16x16x32_bf16(a3, wg[2][3], ac2, 0,0,0);   \
    ac3 = __builtin_amdgcn_mfma_f32_16x16x32_bf16(a3, wg[3][3], ac3, 0,0,0);   \
    ac0 = __builtin_amdgcn_mfma_f32_16x16x32_bf16(a4, wg[0][4], ac0, 0,0,0);   \
    ac1 = __builtin_amdgcn_mfma_f32_16x16x32_bf16(a4, wg[1][4], ac1, 0,0,0);   \
    ac2 = __builtin_amdgcn_mfma_f32_16x16x32_bf16(a4, wg[2][4], ac2, 0,0,0);   \
    ac3 = __builtin_amdgcn_mfma_f32_16x16x32_bf16(a4, wg[3][4], ac3, 0,0,0);   \
    ac0 = __builtin_amdgcn_mfma_f32_16x16x32_bf16(a5, wg[0][5], ac0, 0,0,0);   \
    ac1 = __builtin_amdgcn_mfma_f32_16x16x32_bf16(a5, wg[1][5], ac1, 0,0,0);   \
    ac2 = __builtin_amdgcn_mfma_f32_16x16x32_bf16(a5, wg[2][5], ac2, 0,0,0);   \
    ac3 = __builtin_amdgcn_mfma_f32_16x16x32_bf16(a5, wg[3][5], ac3, 0,0,0);   \
    const float g0 = ac0[0] + bias[0];                                         \
    const float g1 = ac1[0] + bias[1];                                         \
    const float g2 = ac2[0] + bias[2];                                         \
    const float g3 = ac3[0] + bias[3];                                         \
    const float si = 1.f / (1.f + __expf(-g0));                                \
    const float sf = 1.f / (1.f + __expf(-g1));                                \
    const float tg = 1.f - 2.f / (__expf(2.f * g2) + 1.f);                     \
    const float so = 1.f / (1.f + __expf(-g3));                                \
    const float cn = sf * c + si * tg;                                         \
    const float tc = 1.f - 2.f / (__expf(2.f * cn) + 1.f);                     \
    const float hn = so * tc;                                                  \
    const int nxt_ = cur ^ 1;                                                  \
    if (s_ < P_my) { c = cn; zbuf[nxt_][(4*lq)*ZP + 64 + unit] = f2bf(hn); }   \
    bar_lds();                                          /* B2: h ready */      \
    if (w4) {                                                                  \
      const unsigned short* zn_ = zbuf[nxt_];                                  \
      bf16x8 h0f = *(const bf16x8*)(zn_ + abase + 64 +  0);                    \
      bf16x8 h1f = *(const bf16x8*)(zn_ + abase + 64 + 32);                    \
      bf16x8 h2f = *(const bf16x8*)(zn_ + abase + 64 + 64);                    \
      bf16x8 h3f = *(const bf16x8*)(zn_ + abase + 64 + 96);                    \
      f32x4 pa = {0.f,0.f,0.f,0.f}, pb = {0.f,0.f,0.f,0.f};                    \
      pa = __builtin_amdgcn_mfma_f32_16x16x32_bf16(h0f, wd0, pa, 0,0,0);       \
      pb = __builtin_amdgcn_mfma_f32_16x16x32_bf16(h2f, wd2, pb, 0,0,0);       \
      pa = __builtin_amdgcn_mfma_f32_16x16x32_bf16(h1f, wd1, pa, 0,0,0);       \
      pb = __builtin_amdgcn_mfma_f32_16x16x32_bf16(h3f, wd3, pb, 0,0,0);       \
      const float pred_ = pa[0] + pb[0] + bden;                                \
      if (s_ < P_my) {                                                         \
        outb[(size_t)s_ * OUTS] = pred_;                                       \
        if (s_ + 1 >= AV_my)                                                   \
          zbuf[nxt_][(4*lq)*ZP + 16*w + l16] = f2bf(pred_);                    \
      }                                                                        \
      if (s_ + 1 < AV_x) zbuf[nxt_][(4*w)*ZP + l] = f2bf(XNEXT);               \
    }                                                                          \
    cur = nxt_;                                                                \
  } while (0)

    int t4 = 0;
    for (; t4 + 4 <= tsw; t4 += 4) {
        float4 qn = {0.f,0.f,0.f,0.f};
        if (w4 && (t4 + 4 < AV_x))
            qn = *(const float4*)(x + xbase + t4 + 4);
        DO_STEP(t4 + 0, qc.y);
        DO_STEP(t4 + 1, qc.z);
        DO_STEP(t4 + 2, qc.w);
        DO_STEP(t4 + 3, qn.x);
        qc = qn;
    }
    for (; t4 < tsw; ++t4) {
        float xs = 0.f;
        if (w4 && (t4 + 1 < AV_x)) xs = x[xbase + t4 + 1];
        DO_STEP(t4, xs);
    }
#undef DO_STEP

    // ================= PHASE 2: t in [tsw, maxP) — all rows auto ============
    if (tsw < maxP) {
        // reload wg[.][0..3] in place with W_auto = W_hh + W_fold (fp32 add)
        const float* wfold = ws;
        const float* bfold = ws + 4*HH*HH;
        #pragma unroll
        for (int g = 0; g < 4; ++g) {
            const int n = 128*g + 16*w + l16;
            const float* rhh = W_hh + n * HH;
            const float* rfo = wfold + n * HH;
            #pragma unroll
            for (int j = 0; j < 4; ++j) {
                const int k = 32*j + 8*lq;
                bf16x8 r;
                #pragma unroll
                for (int i = 0; i < 8; i++) r[i] = (short)f2bf(rhh[k+i] + rfo[k+i]);
                wg[g][j] = r;
            }
            bias[g] += bfold[n];
        }

        for (int t = tsw; t < maxP; ++t) {
            bar_lds();                                 // single barrier
            const unsigned short* zc = zbuf[cur];
            bf16x8 h0f = *(const bf16x8*)(zc + abase + 64 +  0);
            bf16x8 h1f = *(const bf16x8*)(zc + abase + 64 + 32);
            bf16x8 h2f = *(const bf16x8*)(zc + abase + 64 + 64);
            bf16x8 h3f = *(const bf16x8*)(zc + abase + 64 + 96);

            // deferred pred for t-1 (store rides across barriers)
            if (w4) {
                f32x4 pa = {0.f,0.f,0.f,0.f}, pb = {0.f,0.f,0.f,0.f};
                pa = __builtin_amdgcn_mfma_f32_16x16x32_bf16(h0f, wd0, pa, 0,0,0);
                pb = __builtin_amdgcn_mfma_f32_16x16x32_bf16(h2f, wd2, pb, 0,0,0);
                pa = __builtin_amdgcn_mfma_f32_16x16x32_bf16(h1f, wd1, pa, 0,0,0);
                pb = __builtin_amdgcn_mfma_f32_16x16x32_bf16(h3f, wd3, pb, 0,0,0);
                if (t > tsw && (t - 1) < P_my)
                    outb[(size_t)(t-1) * OUTS] = pa[0] + pb[0] + bden;
            }

            f32x4 ac0 = {0.f,0.f,0.f,0.f}, ac1 = {0.f,0.f,0.f,0.f},
                  ac2 = {0.f,0.f,0.f,0.f}, ac3 = {0.f,0.f,0.f,0.f};
            ac0 = __builtin_amdgcn_mfma_f32_16x16x32_bf16(h0f, wg[0][0], ac0, 0,0,0);
            ac1 = __builtin_amdgcn_mfma_f32_16x16x32_bf16(h0f, wg[1][0], ac1, 0,0,0);
            ac2 = __builtin_amdgcn_mfma_f32_16x16x32_bf16(h0f, wg[2][0], ac2, 0,0,0);
            ac3 = __builtin_amdgcn_mfma_f32_16x16x32_bf16(h0f, wg[3][0], ac3, 0,0,0);
            ac0 = __builtin_amdgcn_mfma_f32_16x16x32_bf16(h1f, wg[0][1], ac0, 0,0,0);
            ac1 = __builtin_amdgcn_mfma_f32_16x16x32_bf16(h1f, wg[1][1], ac1, 0,0,0);
            ac2 = __builtin_amdgcn_mfma_f32_16x16x32_bf16(h1f, wg[2][1], ac2, 0,0,0);
            ac3 = __builtin_amdgcn_mfma_f32_16x16x32_bf16(h1f, wg[3][1], ac3, 0,0,0);
            ac0 = __builtin_amdgcn_mfma_f32_16x16x32_bf16(h2f, wg[0][2], ac0, 0,0,0);
            ac1 = __builtin_amdgcn_mfma_f32_16x16x32_bf16(h2f, wg[1][2], ac1, 0,0,0);
            ac2 = __builtin_amdgcn_mfma_f32_16x16x32_bf16(h2f, wg[2][2], ac2, 0,0,0);
            ac3 = __builtin_amdgcn_mfma_f32_16x16x32_bf16(h2f, wg[3][2], ac3, 0,0,0);
            ac0 = __builtin_amdgcn_mfma_f32_16x16x32_bf16(h3f, wg[0][3], ac0, 0,0,0);
            ac1 = __builtin_amdgcn_mfma_f32_16x16x32_bf16(h3f, wg[1][3], ac1, 0,0,0);
            ac2 = __builtin_amdgcn_mfma_f32_16x16x32_bf16(h3f, wg[2][3], ac2, 0,0,0);
            ac3 = __builtin_amdgcn_mfma_f32_16x16x32_bf16(h3f, wg[3][3], ac3, 0,0,0);

            const float g0 = ac0[0] + bias[0];
            const float g1 = ac1[0] + bias[1];
            const float g2 = ac2[0] + bias[2];
            const float g3 = ac3[0] + bias[3];
            const float si = 1.f / (1.f + __expf(-g0));
            const float sf = 1.f / (1.f + __expf(-g1));
            const float tg = 1.f - 2.f / (__expf(2.f * g2) + 1.f);
            const float so = 1.f / (1.f + __expf(-g3));
            const float cn = sf * c + si * tg;
            const float tc = 1.f - 2.f / (__expf(2.f * cn) + 1.f);
            const float hn = so * tc;

            const int nxt = cur ^ 1;
            if (t < P_my) { c = cn; zbuf[nxt][(4*lq)*ZP + 64 + unit] = f2bf(hn); }
            cur = nxt;
        }

        // epilogue: pred_{maxP-1} from h_{maxP}
        bar_lds();
        if (w4) {
            const unsigned short* zc = zbuf[cur];
            bf16x8 h0f = *(const bf16x8*)(zc + abase + 64 +  0);
            bf16x8 h1f = *(const bf16x8*)(zc + abase + 64 + 32);
            bf16x8 h2f = *(const bf16x8*)(zc + abase + 64 + 64);
            bf16x8 h3f = *(const bf16x8*)(zc + abase + 64 + 96);
            f32x4 pa = {0.f,0.f,0.f,0.f}, pb = {0.f,0.f,0.f,0.f};
            pa = __builtin_amdgcn_mfma_f32_16x16x32_bf16(h0f, wd0, pa, 0,0,0);
            pb = __builtin_amdgcn_mfma_f32_16x16x32_bf16(h2f, wd2, pb, 0,0,0);
            pa = __builtin_amdgcn_mfma_f32_16x16x32_bf16(h1f, wd1, pa, 0,0,0);
            pb = __builtin_amdgcn_mfma_f32_16x16x32_bf16(h3f, wd3, pb, 0,0,0);
            if ((maxP - 1) < P_my)
                outb[(size_t)(maxP-1) * OUTS] = pa[0] + pb[0] + bden;
        }
    }
}

// ---------------------------------------------------------------------------
// Tail: for t >= predict_len[b], out[t][b][f] = x[b][f][t].
// ---------------------------------------------------------------------------
__global__ void tail_copy(const float* __restrict__ x,
                          const int* __restrict__ predict_len,
                          float* __restrict__ out)
{
    __shared__ float tile[64][65];
    const int b  = blockIdx.x;
    const int t0 = blockIdx.y * 64;
    const int P  = predict_len[b];
    if (t0 + 64 <= P) return;

    const int tid = threadIdx.x;         // 256
    const int tt  = tid & 63;
    const int fb  = tid >> 6;
    #pragma unroll
    for (int i = 0; i < 16; i++) {
        int f = fb * 16 + i;
        tile[f][tt] = x[(size_t)b * FF * SS + (size_t)f * SS + t0 + tt];
    }
    __syncthreads();
    const int f2 = tid & 63;
    const int tb = tid >> 6;
    #pragma unroll
    for (int i = 0; i < 16; i++) {
        int tloc = tb * 16 + i;
        int t    = t0 + tloc;
        if (t >= P) out[(size_t)t * BB * FF + (size_t)b * FF + f2] = tile[f2][tloc];
    }
}

extern "C" void kernel_launch(void* const* d_in, const int* in_sizes, int n_in,
                              void* d_out, int out_size, void* d_ws, size_t ws_size,
                              hipStream_t stream) {
    const float* x       = (const float*)d_in[0];
    const int*   avail   = (const int*)  d_in[1];
    const int*   plen    = (const int*)  d_in[2];
    const float* W_ih    = (const float*)d_in[3];
    const float* W_hh    = (const float*)d_in[4];
    const float* b_ih    = (const float*)d_in[5];
    const float* b_hh    = (const float*)d_in[6];
    const float* W_den   = (const float*)d_in[7];
    const float* b_den   = (const float*)d_in[8];
    const float* init_ch = (const float*)d_in[9];
    float*       out     = (float*)d_out;
    float*       ws      = (float*)d_ws;       // needs 264 KB

    fold_kernel<<<dim3(4*HH), dim3(HH), 0, stream>>>(W_ih, W_den, b_den, ws);
    tail_copy<<<dim3(BB, SS/64), dim3(256), 0, stream>>>(x, plen, out);
    lstm_mfma_kernel<<<dim3(BB/4), dim3(512), 0, stream>>>(
        x, avail, plen, W_ih, W_hh, b_ih, b_hh, W_den, b_den, init_ch, ws, out);
}